// Round 7
// baseline (334.491 us; speedup 1.0000x reference)
//
#include <hip/hip_runtime.h>

#define B_  4
#define C_  256     // C_IN == LATENT == 256
#define N_  4096    // H*W
#define SCALE 0.0625f   // 1/sqrt(256)

typedef short s8v __attribute__((ext_vector_type(8)));
typedef float f4v __attribute__((ext_vector_type(4)));

// round-to-nearest-even fp32 -> bf16 (values are finite; no NaN handling needed)
static __device__ __forceinline__ ushort f2bf(float f) {
  union { float f; uint u; } v; v.f = f;
  return (ushort)((v.u + 0x7FFFu + ((v.u >> 16) & 1u)) >> 16);
}

// ---------------------------------------------------------------------------
// xpose_cast: x [b][c][n] fp32  ->  x_t [b][n][c] bf16.  (unchanged, R6-pass)
// ---------------------------------------------------------------------------
__global__ __launch_bounds__(256) void xpose_cast(
    const float* __restrict__ x, ushort* __restrict__ x_t)
{
  const int b  = blockIdx.z;
  const int c0 = blockIdx.y * 64;
  const int n0 = blockIdx.x * 64;
  __shared__ float t[64][65];

  const int tc = threadIdx.x >> 4;
  const int tn = (threadIdx.x & 15) * 4;
  #pragma unroll
  for (int cc = 0; cc < 64; cc += 16) {
    float4 v = *(const float4*)(x + (size_t)(b * C_ + c0 + cc + tc) * N_ + n0 + tn);
    t[cc + tc][tn + 0] = v.x;
    t[cc + tc][tn + 1] = v.y;
    t[cc + tc][tn + 2] = v.z;
    t[cc + tc][tn + 3] = v.w;
  }
  __syncthreads();

  const int on = threadIdx.x >> 2;
  const int oc = (threadIdx.x & 3) * 16;
  union { ushort us[16]; uint4 q[2]; } o;
  #pragma unroll
  for (int i = 0; i < 16; ++i) o.us[i] = f2bf(t[oc + i][on]);
  ushort* dst = x_t + (size_t)(b * N_ + n0 + on) * C_ + c0 + oc;
  *(uint4*)dst       = o.q[0];
  *(uint4*)(dst + 8) = o.q[1];
}

// ---------------------------------------------------------------------------
// qkv_mfma: bf16 MFMA projection (unchanged, R6-pass).
// grid (8, 4, 12), block 256.
// ---------------------------------------------------------------------------
__global__ __launch_bounds__(256, 2) void qkv_mfma(
    const ushort* __restrict__ x_t,
    const float* __restrict__ Wq, const float* __restrict__ bq,
    const float* __restrict__ Wk, const float* __restrict__ bk,
    const float* __restrict__ Wv, const float* __restrict__ bv,
    ushort* __restrict__ q_t, ushort* __restrict__ k_t, ushort* __restrict__ v_bf)
{
  const int p = blockIdx.z >> 2;
  const int b = blockIdx.z & 3;
  const float* W  = (p == 0) ? Wq : (p == 1) ? Wk : Wv;
  const float* bi = (p == 0) ? bq : (p == 1) ? bk : bv;
  const int l0    = blockIdx.y * 64;
  const int nseg  = blockIdx.x * 512;

  const int tid  = threadIdx.x;
  const int lane = tid & 63;
  const int wave = tid >> 6;
  const int l16  = lane & 15;
  const int quad = lane >> 4;

  __shared__ __align__(16) ushort w_lds[64 * 264];
  __shared__ __align__(16) ushort x_lds[64 * 264];

  for (int g = tid; g < 4096; g += 256) {
    int row = g >> 6, col4 = (g & 63) * 4;
    float4 wv = *(const float4*)(W + (size_t)(l0 + row) * 256 + col4);
    *(ushort4*)&w_lds[row * 264 + col4] =
        make_ushort4(f2bf(wv.x), f2bf(wv.y), f2bf(wv.z), f2bf(wv.w));
  }
  __syncthreads();

  s8v kw[4][8];
  #pragma unroll
  for (int lt = 0; lt < 4; ++lt)
    #pragma unroll
    for (int cs = 0; cs < 8; ++cs)
      kw[lt][cs] = *(const s8v*)&w_lds[(lt * 16 + l16) * 264 + quad * 8 + cs * 32];

  float bias_l[4];
  #pragma unroll
  for (int lt = 0; lt < 4; ++lt) bias_l[lt] = bi[l0 + lt * 16 + l16];

  for (int it = 0; it < 8; ++it) {
    const int n0 = nseg + it * 64;
    {
      const ushort* xseg = x_t + (size_t)(b * N_ + n0) * C_;
      #pragma unroll
      for (int k = 0; k < 8; ++k) {
        int c = tid + k * 256;
        uint4 d = *(const uint4*)(xseg + (size_t)c * 8);
        *(uint4*)&x_lds[(c >> 5) * 264 + (c & 31) * 8] = d;
      }
    }
    __syncthreads();

    f4v s[4];
    #pragma unroll
    for (int lt = 0; lt < 4; ++lt) s[lt] = (f4v){0.f, 0.f, 0.f, 0.f};
    const ushort* xa_base = x_lds + (wave * 16 + l16) * 264 + quad * 8;
    #pragma unroll
    for (int cs = 0; cs < 8; ++cs) {
      s8v xa = *(const s8v*)(xa_base + cs * 32);
      #pragma unroll
      for (int lt = 0; lt < 4; ++lt)
        s[lt] = __builtin_amdgcn_mfma_f32_16x16x32_bf16(xa, kw[lt][cs], s[lt], 0, 0, 0);
    }

    const int nb = n0 + wave * 16 + quad * 4;
    if (p < 2) {
      ushort* outp = (p == 0) ? q_t : k_t;
      #pragma unroll
      for (int lt = 0; lt < 4; ++lt) {
        const int l = l0 + lt * 16 + l16;
        #pragma unroll
        for (int r = 0; r < 4; ++r)
          outp[(size_t)(b * N_ + nb + r) * C_ + l] = f2bf(s[lt][r] + bias_l[lt]);
      }
    } else {
      #pragma unroll
      for (int lt = 0; lt < 4; ++lt) {
        const int c_out = l0 + lt * 16 + l16;
        *(ushort4*)&v_bf[(size_t)(b * C_ + c_out) * N_ + nb] =
            make_ushort4(f2bf(s[lt][0] + bias_l[lt]), f2bf(s[lt][1] + bias_l[lt]),
                         f2bf(s[lt][2] + bias_l[lt]), f2bf(s[lt][3] + bias_l[lt]));
      }
    }
    __syncthreads();
  }
}

// ---------------------------------------------------------------------------
// flash6: pipelined fused attention, NO numerator atomics.
//   Block = 4 waves, TJ=64, BI=64, 32 iters over an i-segment of 2048.
//   grid (64, 2, 4) = 512 blocks = 2 blocks/CU (LDS 76.8 KB, VGPR<=256).
//   q staged double-buffered: glb loads for t+1 issue at TOP of iter t,
//   ds_write to alternate buffer after barrier A -> NO barrier waits on
//   global latency. Hazards: qbuf parity & p_lds read/write separated by
//   the A/B barrier chain (verified ordering).
//   QK: wave (j-pair = w&1, i-pair = w>>1): 2 tj x 2 ti tiles, kf regs.
//   PV: wave owns c-range w*64, all 64 tj: acc[4][4].
//   Output: bf16 partials res{0,1}[b][n][c] via plain 8B stores (r-index of
//   C-layout is c-consecutive); den via tiny atomics. Normalization+sum of
//   partials deferred to out_mfma.
// ---------------------------------------------------------------------------
__global__ __launch_bounds__(256, 2) void flash6(
    const ushort* __restrict__ q_t, const ushort* __restrict__ k_t,
    const ushort* __restrict__ v_bf, ushort* __restrict__ res0,
    ushort* __restrict__ res1, float* __restrict__ den)
{
  const int tid  = threadIdx.x;
  const int lane = tid & 63;
  const int wave = tid >> 6;
  const int l16  = lane & 15;
  const int quad = lane >> 4;
  const int jw    = blockIdx.x * 64;
  const int seg   = blockIdx.y;
  const int ibase = seg * 2048;
  const int b     = blockIdx.z;

  const int wqk_j = wave & 1;      // tj = wqk_j*32 + jt*16
  const int wqk_i = wave >> 1;     // i_loc = (wqk_i*2 + itile)*16

  __shared__ __align__(16) ushort q_lds[2][64 * 264];
  __shared__ __align__(16) ushort p_lds[64 * 72];

  // K fragments: wave's 32 tj x 256 c, resident (64 VGPR)
  s8v kf[2][8];
  #pragma unroll
  for (int jt = 0; jt < 2; ++jt) {
    const ushort* kp = k_t + (size_t)(b * N_ + jw + wqk_j * 32 + jt * 16 + l16) * C_ + quad * 8;
    #pragma unroll
    for (int cs = 0; cs < 8; ++cs) kf[jt][cs] = *(const s8v*)(kp + cs * 32);
  }

  f4v acc[4][4];   // [m: c-tile][t: tj-tile]; c = wave*64+m*16+quad*4+r, tj = jw+t*16+l16
  #pragma unroll
  for (int m = 0; m < 4; ++m)
    #pragma unroll
    for (int t = 0; t < 4; ++t) acc[m][t] = (f4v){0.f, 0.f, 0.f, 0.f};
  float dacc0 = 0.f, dacc1 = 0.f;

  const ushort* qseg   = q_t + ((size_t)(b * N_) + ibase) * C_;   // [2048][256]
  const ushort* vbase0 = v_bf + (size_t)(b * C_ + wave * 64 + l16) * N_ + quad * 8;

  // prologue: stage iter 0 into buf 0
  #pragma unroll
  for (int k = 0; k < 8; ++k) {
    int c = tid + k * 256;
    uint4 d = *(const uint4*)(qseg + (size_t)c * 8);
    *(uint4*)&q_lds[0][(c >> 5) * 264 + (c & 31) * 8] = d;
  }
  __syncthreads();

  for (int t = 0; t < 32; ++t) {
    const int i0 = ibase + t * 64;
    const ushort* qbuf = q_lds[t & 1];

    // issue q global loads for t+1 (land during QK phase)
    uint4 qn[8];
    if (t < 31) {
      const ushort* qnext = qseg + (size_t)(t + 1) * 64 * C_;
      #pragma unroll
      for (int k = 0; k < 8; ++k)
        qn[k] = *(const uint4*)(qnext + (size_t)(tid + k * 256) * 8);
    }
    // issue v loads for this iter (consumed after barrier B)
    s8v av[4][2];
    #pragma unroll
    for (int m = 0; m < 4; ++m)
      #pragma unroll
      for (int ks = 0; ks < 2; ++ks)
        av[m][ks] = *(const s8v*)(vbase0 + (size_t)(m * 16) * N_ + i0 + ks * 32);

    // ---- QK: 2 i-tiles x 2 tj-tiles; P values held in regs until barrier A ----
    ushort4 pw[2][2];
    #pragma unroll
    for (int itile = 0; itile < 2; ++itile) {
      const int i_loc = (wqk_i * 2 + itile) * 16;
      f4v s0 = (f4v){0.f, 0.f, 0.f, 0.f};
      f4v s1 = (f4v){0.f, 0.f, 0.f, 0.f};
      const ushort* qa_base = qbuf + (i_loc + l16) * 264 + quad * 8;
      #pragma unroll
      for (int cs = 0; cs < 8; ++cs) {
        s8v qa = *(const s8v*)(qa_base + cs * 32);
        s0 = __builtin_amdgcn_mfma_f32_16x16x32_bf16(qa, kf[0][cs], s0, 0, 0, 0);
        s1 = __builtin_amdgcn_mfma_f32_16x16x32_bf16(qa, kf[1][cs], s1, 0, 0, 0);
      }
      {
        float e0 = __expf(s0[0] * SCALE), e1 = __expf(s0[1] * SCALE);
        float e2 = __expf(s0[2] * SCALE), e3 = __expf(s0[3] * SCALE);
        dacc0 += (e0 + e1) + (e2 + e3);
        pw[itile][0] = make_ushort4(f2bf(e0), f2bf(e1), f2bf(e2), f2bf(e3));
      }
      {
        float e0 = __expf(s1[0] * SCALE), e1 = __expf(s1[1] * SCALE);
        float e2 = __expf(s1[2] * SCALE), e3 = __expf(s1[3] * SCALE);
        dacc1 += (e0 + e1) + (e2 + e3);
        pw[itile][1] = make_ushort4(f2bf(e0), f2bf(e1), f2bf(e2), f2bf(e3));
      }
    }

    __syncthreads();   // barrier A: all waves' PV(t-1) p_lds reads complete

    // P writes (C-layout)
    #pragma unroll
    for (int itile = 0; itile < 2; ++itile) {
      const int i_loc = (wqk_i * 2 + itile) * 16;
      *(ushort4*)&p_lds[(wqk_j * 32 + l16) * 72 + i_loc + quad * 4]      = pw[itile][0];
      *(ushort4*)&p_lds[(wqk_j * 32 + 16 + l16) * 72 + i_loc + quad * 4] = pw[itile][1];
    }
    // q(t+1) ds_write into alternate buffer (vmcnt wait overlapped with QK)
    if (t < 31) {
      #pragma unroll
      for (int k = 0; k < 8; ++k) {
        int c = tid + k * 256;
        *(uint4*)&q_lds[(t + 1) & 1][(c >> 5) * 264 + (c & 31) * 8] = qn[k];
      }
    }

    __syncthreads();   // barrier B: P + q(t+1) ready (LDS-only waits)

    // ---- PV: 4 c-tiles x 4 tj-tiles, A = av regs, B from p_lds ----
    #pragma unroll
    for (int ks = 0; ks < 2; ++ks) {
      s8v pb[4];
      #pragma unroll
      for (int t4 = 0; t4 < 4; ++t4)
        pb[t4] = *(const s8v*)&p_lds[(t4 * 16 + l16) * 72 + ks * 32 + quad * 8];
      #pragma unroll
      for (int m = 0; m < 4; ++m)
        #pragma unroll
        for (int t4 = 0; t4 < 4; ++t4)
          acc[m][t4] = __builtin_amdgcn_mfma_f32_16x16x32_bf16(av[m][ks], pb[t4], acc[m][t4], 0, 0, 0);
    }
  }

  // ---- denom: lanes l, l^16, l^32 share tj; butterfly then atomic ----
  dacc0 += __shfl_xor(dacc0, 16);  dacc0 += __shfl_xor(dacc0, 32);
  dacc1 += __shfl_xor(dacc1, 16);  dacc1 += __shfl_xor(dacc1, 32);
  if (lane < 16) {
    atomicAdd(&den[b * N_ + jw + wqk_j * 32 + lane], dacc0);
    atomicAdd(&den[b * N_ + jw + wqk_j * 32 + 16 + lane], dacc1);
  }

  // ---- numerator partial: plain bf16 stores, [b][n][c] layout (8B/store) ----
  ushort* rp = seg ? res1 : res0;
  #pragma unroll
  for (int m = 0; m < 4; ++m) {
    const int c0 = wave * 64 + m * 16 + quad * 4;
    #pragma unroll
    for (int t4 = 0; t4 < 4; ++t4) {
      const int j = jw + t4 * 16 + l16;
      *(ushort4*)&rp[(size_t)(b * N_ + j) * C_ + c0] =
          make_ushort4(f2bf(acc[m][t4][0]), f2bf(acc[m][t4][1]),
                       f2bf(acc[m][t4][2]), f2bf(acc[m][t4][3]));
    }
  }
}

// ---------------------------------------------------------------------------
// out_mfma: out[b][co][n] = bo[co] + Wo[co][:]·(res0+res1)[b][n][:] / den[b][n]
//   Same structure as qkv_mfma; accumulates TWO A-streams (res0, res1) into
//   one accumulator (= GEMM of the partial sum, no separate add pass).
//   D rows are n-consecutive per lane -> coalesced float4 stores.
// grid (16, 4, 4) = (n-seg of 256, co-range of 64, b), block 256.
// ---------------------------------------------------------------------------
__global__ __launch_bounds__(256, 2) void out_mfma(
    const ushort* __restrict__ res0, const ushort* __restrict__ res1,
    const float* __restrict__ Wo, const float* __restrict__ bo,
    const float* __restrict__ den, float* __restrict__ out)
{
  const int b    = blockIdx.z;
  const int co0  = blockIdx.y * 64;
  const int nseg = blockIdx.x * 256;

  const int tid  = threadIdx.x;
  const int lane = tid & 63;
  const int wave = tid >> 6;
  const int l16  = lane & 15;
  const int quad = lane >> 4;

  __shared__ __align__(16) ushort w_lds[64 * 264];
  __shared__ __align__(16) ushort r_lds[2][64 * 264];

  for (int g = tid; g < 4096; g += 256) {
    int row = g >> 6, col4 = (g & 63) * 4;
    float4 wv = *(const float4*)(Wo + (size_t)(co0 + row) * 256 + col4);
    *(ushort4*)&w_lds[row * 264 + col4] =
        make_ushort4(f2bf(wv.x), f2bf(wv.y), f2bf(wv.z), f2bf(wv.w));
  }
  __syncthreads();

  s8v kw[4][8];
  #pragma unroll
  for (int lt = 0; lt < 4; ++lt)
    #pragma unroll
    for (int cs = 0; cs < 8; ++cs)
      kw[lt][cs] = *(const s8v*)&w_lds[(lt * 16 + l16) * 264 + quad * 8 + cs * 32];

  float bias_l[4];
  #pragma unroll
  for (int lt = 0; lt < 4; ++lt) bias_l[lt] = bo[co0 + lt * 16 + l16];

  for (int it = 0; it < 4; ++it) {
    const int n0 = nseg + it * 64;
    {
      const ushort* r0 = res0 + (size_t)(b * N_ + n0) * C_;
      const ushort* r1 = res1 + (size_t)(b * N_ + n0) * C_;
      #pragma unroll
      for (int k = 0; k < 8; ++k) {
        int c = tid + k * 256;
        uint4 d0 = *(const uint4*)(r0 + (size_t)c * 8);
        uint4 d1 = *(const uint4*)(r1 + (size_t)c * 8);
        *(uint4*)&r_lds[0][(c >> 5) * 264 + (c & 31) * 8] = d0;
        *(uint4*)&r_lds[1][(c >> 5) * 264 + (c & 31) * 8] = d1;
      }
    }
    __syncthreads();

    f4v s[4];
    #pragma unroll
    for (int lt = 0; lt < 4; ++lt) s[lt] = (f4v){0.f, 0.f, 0.f, 0.f};
    #pragma unroll
    for (int buf = 0; buf < 2; ++buf) {
      const ushort* ra_base = r_lds[buf] + (wave * 16 + l16) * 264 + quad * 8;
      #pragma unroll
      for (int cs = 0; cs < 8; ++cs) {
        s8v ra = *(const s8v*)(ra_base + cs * 32);
        #pragma unroll
        for (int lt = 0; lt < 4; ++lt)
          s[lt] = __builtin_amdgcn_mfma_f32_16x16x32_bf16(ra, kw[lt][cs], s[lt], 0, 0, 0);
      }
    }

    const int nb = n0 + wave * 16 + quad * 4;
    float4 dv = *(const float4*)(den + (size_t)b * N_ + nb);
    const float di0 = 1.0f / dv.x, di1 = 1.0f / dv.y, di2 = 1.0f / dv.z, di3 = 1.0f / dv.w;
    #pragma unroll
    for (int lt = 0; lt < 4; ++lt) {
      const int co = co0 + lt * 16 + l16;
      *(float4*)&out[(size_t)(b * C_ + co) * N_ + nb] =
          make_float4(s[lt][0] * di0 + bias_l[lt], s[lt][1] * di1 + bias_l[lt],
                      s[lt][2] * di2 + bias_l[lt], s[lt][3] * di3 + bias_l[lt]);
    }
    __syncthreads();
  }
}

// ---------------------------------------------------------------------------
extern "C" void kernel_launch(void* const* d_in, const int* in_sizes, int n_in,
                              void* d_out, int out_size, void* d_ws, size_t ws_size,
                              hipStream_t stream)
{
  const float* x  = (const float*)d_in[0];
  const float* Wq = (const float*)d_in[1];
  const float* bq = (const float*)d_in[2];
  const float* Wk = (const float*)d_in[3];
  const float* bk = (const float*)d_in[4];
  const float* Wv = (const float*)d_in[5];
  const float* bv = (const float*)d_in[6];
  const float* Wo = (const float*)d_in[7];
  const float* bo = (const float*)d_in[8];
  float* out = (float*)d_out;

  // workspace layout (~48.1 MB):
  //   q_t   [B][N][L] bf16 : 8 MB   (transposed)
  //   k_t   [B][N][L] bf16 : 8 MB   (transposed)
  //   v_bf  [B][L][N] bf16 : 8 MB   (natural)
  //   res0  [B][N][L] bf16 : 8 MB   (numerator partial, i-segment 0)
  //   res1  [B][N][L] bf16 : 8 MB   (numerator partial, i-segment 1)
  //   den   [B][N]    fp32 : 64 KB  (softmax denominators, atomic target)
  //   x_t   [B][N][C] bf16 : 8 MB   (transposed+cast input)
  char* ws = (char*)d_ws;
  ushort* q_t  = (ushort*)(ws);
  ushort* k_t  = (ushort*)(ws + (size_t)8  * 1024 * 1024);
  ushort* v_bf = (ushort*)(ws + (size_t)16 * 1024 * 1024);
  ushort* res0 = (ushort*)(ws + (size_t)24 * 1024 * 1024);
  ushort* res1 = (ushort*)(ws + (size_t)32 * 1024 * 1024);
  float*  den  = (float*) (ws + (size_t)40 * 1024 * 1024);
  ushort* x_t  = (ushort*)(ws + (size_t)40 * 1024 * 1024 + 65536);

  // only den needs zeroing now (res partials are fully overwritten)
  (void)hipMemsetAsync(den, 0, (size_t)B_ * N_ * sizeof(float), stream);

  xpose_cast<<<dim3(64, 4, 4), dim3(256), 0, stream>>>(x, x_t);
  qkv_mfma <<<dim3(8, 4, 12),  dim3(256), 0, stream>>>(x_t, Wq, bq, Wk, bk, Wv, bv, q_t, k_t, v_bf);
  flash6   <<<dim3(64, 2, 4),  dim3(256), 0, stream>>>(q_t, k_t, v_bf, res0, res1, den);
  out_mfma <<<dim3(16, 4, 4),  dim3(256), 0, stream>>>(res0, res1, Wo, bo, den, out);
}

// Round 8
// 215.727 us; speedup vs baseline: 1.5505x; 1.5505x over previous
//
#include <hip/hip_runtime.h>

#define B_  4
#define C_  256     // C_IN == LATENT == 256
#define N_  4096    // H*W
#define SCALE 0.0625f   // 1/sqrt(256)

typedef short s8v __attribute__((ext_vector_type(8)));
typedef float f4v __attribute__((ext_vector_type(4)));

// round-to-nearest-even fp32 -> bf16 (values are finite; no NaN handling needed)
static __device__ __forceinline__ ushort f2bf(float f) {
  union { float f; uint u; } v; v.f = f;
  return (ushort)((v.u + 0x7FFFu + ((v.u >> 16) & 1u)) >> 16);
}

// ---------------------------------------------------------------------------
// xpose_cast: x [b][c][n] fp32  ->  x_t [b][n][c] bf16.  (unchanged, passing)
// ---------------------------------------------------------------------------
__global__ __launch_bounds__(256) void xpose_cast(
    const float* __restrict__ x, ushort* __restrict__ x_t)
{
  const int b  = blockIdx.z;
  const int c0 = blockIdx.y * 64;
  const int n0 = blockIdx.x * 64;
  __shared__ float t[64][65];

  const int tc = threadIdx.x >> 4;
  const int tn = (threadIdx.x & 15) * 4;
  #pragma unroll
  for (int cc = 0; cc < 64; cc += 16) {
    float4 v = *(const float4*)(x + (size_t)(b * C_ + c0 + cc + tc) * N_ + n0 + tn);
    t[cc + tc][tn + 0] = v.x;
    t[cc + tc][tn + 1] = v.y;
    t[cc + tc][tn + 2] = v.z;
    t[cc + tc][tn + 3] = v.w;
  }
  __syncthreads();

  const int on = threadIdx.x >> 2;
  const int oc = (threadIdx.x & 3) * 16;
  union { ushort us[16]; uint4 q[2]; } o;
  #pragma unroll
  for (int i = 0; i < 16; ++i) o.us[i] = f2bf(t[oc + i][on]);
  ushort* dst = x_t + (size_t)(b * N_ + n0 + on) * C_ + c0 + oc;
  *(uint4*)dst       = o.q[0];
  *(uint4*)(dst + 8) = o.q[1];
}

// ---------------------------------------------------------------------------
// qkv_mfma: bf16 MFMA projection (unchanged, passing).
// grid (8, 4, 12), block 256.
// ---------------------------------------------------------------------------
__global__ __launch_bounds__(256, 2) void qkv_mfma(
    const ushort* __restrict__ x_t,
    const float* __restrict__ Wq, const float* __restrict__ bq,
    const float* __restrict__ Wk, const float* __restrict__ bk,
    const float* __restrict__ Wv, const float* __restrict__ bv,
    ushort* __restrict__ q_t, ushort* __restrict__ k_t, ushort* __restrict__ v_bf)
{
  const int p = blockIdx.z >> 2;
  const int b = blockIdx.z & 3;
  const float* W  = (p == 0) ? Wq : (p == 1) ? Wk : Wv;
  const float* bi = (p == 0) ? bq : (p == 1) ? bk : bv;
  const int l0    = blockIdx.y * 64;
  const int nseg  = blockIdx.x * 512;

  const int tid  = threadIdx.x;
  const int lane = tid & 63;
  const int wave = tid >> 6;
  const int l16  = lane & 15;
  const int quad = lane >> 4;

  __shared__ __align__(16) ushort w_lds[64 * 264];
  __shared__ __align__(16) ushort x_lds[64 * 264];

  for (int g = tid; g < 4096; g += 256) {
    int row = g >> 6, col4 = (g & 63) * 4;
    float4 wv = *(const float4*)(W + (size_t)(l0 + row) * 256 + col4);
    *(ushort4*)&w_lds[row * 264 + col4] =
        make_ushort4(f2bf(wv.x), f2bf(wv.y), f2bf(wv.z), f2bf(wv.w));
  }
  __syncthreads();

  s8v kw[4][8];
  #pragma unroll
  for (int lt = 0; lt < 4; ++lt)
    #pragma unroll
    for (int cs = 0; cs < 8; ++cs)
      kw[lt][cs] = *(const s8v*)&w_lds[(lt * 16 + l16) * 264 + quad * 8 + cs * 32];

  float bias_l[4];
  #pragma unroll
  for (int lt = 0; lt < 4; ++lt) bias_l[lt] = bi[l0 + lt * 16 + l16];

  for (int it = 0; it < 8; ++it) {
    const int n0 = nseg + it * 64;
    {
      const ushort* xseg = x_t + (size_t)(b * N_ + n0) * C_;
      #pragma unroll
      for (int k = 0; k < 8; ++k) {
        int c = tid + k * 256;
        uint4 d = *(const uint4*)(xseg + (size_t)c * 8);
        *(uint4*)&x_lds[(c >> 5) * 264 + (c & 31) * 8] = d;
      }
    }
    __syncthreads();

    f4v s[4];
    #pragma unroll
    for (int lt = 0; lt < 4; ++lt) s[lt] = (f4v){0.f, 0.f, 0.f, 0.f};
    const ushort* xa_base = x_lds + (wave * 16 + l16) * 264 + quad * 8;
    #pragma unroll
    for (int cs = 0; cs < 8; ++cs) {
      s8v xa = *(const s8v*)(xa_base + cs * 32);
      #pragma unroll
      for (int lt = 0; lt < 4; ++lt)
        s[lt] = __builtin_amdgcn_mfma_f32_16x16x32_bf16(xa, kw[lt][cs], s[lt], 0, 0, 0);
    }

    const int nb = n0 + wave * 16 + quad * 4;
    if (p < 2) {
      ushort* outp = (p == 0) ? q_t : k_t;
      #pragma unroll
      for (int lt = 0; lt < 4; ++lt) {
        const int l = l0 + lt * 16 + l16;
        #pragma unroll
        for (int r = 0; r < 4; ++r)
          outp[(size_t)(b * N_ + nb + r) * C_ + l] = f2bf(s[lt][r] + bias_l[lt]);
      }
    } else {
      #pragma unroll
      for (int lt = 0; lt < 4; ++lt) {
        const int c_out = l0 + lt * 16 + l16;
        *(ushort4*)&v_bf[(size_t)(b * C_ + c_out) * N_ + nb] =
            make_ushort4(f2bf(s[lt][0] + bias_l[lt]), f2bf(s[lt][1] + bias_l[lt]),
                         f2bf(s[lt][2] + bias_l[lt]), f2bf(s[lt][3] + bias_l[lt]));
      }
    }
    __syncthreads();
  }
}

// ---------------------------------------------------------------------------
// flash7: EXACT flash4 K-loop (best verified: 126 us) + coalesced bf16
// partial epilogue (no numerator atomics).
//   Block = 8 waves, TJ=128, BI=64, 32 iters over i-segment of 2048.
//   Epilogue: block assembles its 64j x 256c tile in q_lds (free after the
//   K-loop), then streams fully-coalesced 16B/lane rows to res{0,1}[b][n][c]
//   -> every 64B line written whole, once (fixes R7's 395 MB amplification).
// grid (32, 2, 4) = (tj-blocks, i-segments, batch), block 512 (8 waves).
// ---------------------------------------------------------------------------
__global__ __launch_bounds__(512, 2) void flash7(
    const ushort* __restrict__ q_t, const ushort* __restrict__ k_t,
    const ushort* __restrict__ v_bf, ushort* __restrict__ res0,
    ushort* __restrict__ res1, float* __restrict__ den)
{
  const int tid  = threadIdx.x;
  const int lane = tid & 63;
  const int wave = tid >> 6;
  const int l16  = lane & 15;
  const int quad = lane >> 4;
  const int jw    = blockIdx.x * 128;        // block tj base
  const int seg   = blockIdx.y;
  const int ibase = seg * 2048;              // i-segment base
  const int b     = blockIdx.z;

  const int wqk_j = wave & 3;                // QK: tj-pair index
  const int wqk_i = wave >> 2;               // QK: i-pair index
  const int wpv_c = wave & 3;                // PV: c-range (w&3)*64
  const int wpv_j = wave >> 2;               // PV: tj-range (w>>2)*64

  __shared__ __align__(16) ushort q_lds[64 * 264];   // [i][c], +8 pad/row; reused by epilogue
  __shared__ __align__(16) ushort p_lds[128 * 72];   // [tj][ti], +8 pad/row

  // K fragments: wave's 32 tj x 256 c, resident whole kernel (64 VGPR)
  s8v kf[2][8];
  #pragma unroll
  for (int jt = 0; jt < 2; ++jt) {
    const ushort* kp = k_t + (size_t)(b * N_ + jw + wqk_j * 32 + jt * 16 + l16) * C_ + quad * 8;
    #pragma unroll
    for (int cs = 0; cs < 8; ++cs) kf[jt][cs] = *(const s8v*)(kp + cs * 32);
  }

  f4v acc[4][4];
  #pragma unroll
  for (int m = 0; m < 4; ++m)
    #pragma unroll
    for (int t = 0; t < 4; ++t) acc[m][t] = (f4v){0.f, 0.f, 0.f, 0.f};
  float dacc0 = 0.f, dacc1 = 0.f;

  const ushort* vbase0 = v_bf + (size_t)(b * C_ + wpv_c * 64 + l16) * N_ + quad * 8;

  for (int it = 0; it < 32; ++it) {
    const int i0 = ibase + it * 64;

    // stage q-chunk [64 i][256 c] -> LDS
    {
      const ushort* qseg = q_t + ((size_t)(b * N_) + i0) * C_;
      int c0 = tid, c1 = tid + 512, c2 = tid + 1024, c3 = tid + 1536;
      uint4 d0 = *(const uint4*)(qseg + (size_t)c0 * 8);
      uint4 d1 = *(const uint4*)(qseg + (size_t)c1 * 8);
      uint4 d2 = *(const uint4*)(qseg + (size_t)c2 * 8);
      uint4 d3 = *(const uint4*)(qseg + (size_t)c3 * 8);
      *(uint4*)&q_lds[(c0 >> 5) * 264 + (c0 & 31) * 8] = d0;
      *(uint4*)&q_lds[(c1 >> 5) * 264 + (c1 & 31) * 8] = d1;
      *(uint4*)&q_lds[(c2 >> 5) * 264 + (c2 & 31) * 8] = d2;
      *(uint4*)&q_lds[(c3 >> 5) * 264 + (c3 & 31) * 8] = d3;
    }

    // v A-frags: issue now, consumed after P-barrier
    s8v av[4][2];
    #pragma unroll
    for (int m = 0; m < 4; ++m)
      #pragma unroll
      for (int ks = 0; ks < 2; ++ks)
        av[m][ks] = *(const s8v*)(vbase0 + (size_t)(m * 16) * N_ + i0 + ks * 32);

    __syncthreads();   // q ready

    // QK: 2 i-tiles x 2 tj-tiles, A from LDS, B from registers
    #pragma unroll
    for (int itile = 0; itile < 2; ++itile) {
      const int i_loc = (wqk_i * 2 + itile) * 16;
      f4v s0 = (f4v){0.f, 0.f, 0.f, 0.f};
      f4v s1 = (f4v){0.f, 0.f, 0.f, 0.f};
      const ushort* qa_base = q_lds + (i_loc + l16) * 264 + quad * 8;
      #pragma unroll
      for (int cs = 0; cs < 8; ++cs) {
        s8v qa = *(const s8v*)(qa_base + cs * 32);
        s0 = __builtin_amdgcn_mfma_f32_16x16x32_bf16(qa, kf[0][cs], s0, 0, 0, 0);
        s1 = __builtin_amdgcn_mfma_f32_16x16x32_bf16(qa, kf[1][cs], s1, 0, 0, 0);
      }
      {
        float e0 = __expf(s0[0] * SCALE), e1 = __expf(s0[1] * SCALE);
        float e2 = __expf(s0[2] * SCALE), e3 = __expf(s0[3] * SCALE);
        dacc0 += (e0 + e1) + (e2 + e3);
        *(ushort4*)&p_lds[(wqk_j * 32 + l16) * 72 + i_loc + quad * 4] =
            make_ushort4(f2bf(e0), f2bf(e1), f2bf(e2), f2bf(e3));
      }
      {
        float e0 = __expf(s1[0] * SCALE), e1 = __expf(s1[1] * SCALE);
        float e2 = __expf(s1[2] * SCALE), e3 = __expf(s1[3] * SCALE);
        dacc1 += (e0 + e1) + (e2 + e3);
        *(ushort4*)&p_lds[(wqk_j * 32 + 16 + l16) * 72 + i_loc + quad * 4] =
            make_ushort4(f2bf(e0), f2bf(e1), f2bf(e2), f2bf(e3));
      }
    }

    __syncthreads();   // P ready (also drains av loads)

    // PV: 4 c-tiles x 4 tj-tiles, A = av regs, B from p_lds
    #pragma unroll
    for (int ks = 0; ks < 2; ++ks) {
      s8v pb[4];
      #pragma unroll
      for (int t = 0; t < 4; ++t)
        pb[t] = *(const s8v*)&p_lds[(wpv_j * 64 + t * 16 + l16) * 72 + ks * 32 + quad * 8];
      #pragma unroll
      for (int m = 0; m < 4; ++m)
        #pragma unroll
        for (int t = 0; t < 4; ++t)
          acc[m][t] = __builtin_amdgcn_mfma_f32_16x16x32_bf16(av[m][ks], pb[t], acc[m][t], 0, 0, 0);
    }
  }

  // ---- denom: lanes l, l^16, l^32 share tj; butterfly then atomic ----
  dacc0 += __shfl_xor(dacc0, 16);  dacc0 += __shfl_xor(dacc0, 32);
  dacc1 += __shfl_xor(dacc1, 16);  dacc1 += __shfl_xor(dacc1, 32);
  if (lane < 16) {
    atomicAdd(&den[b * N_ + jw + wqk_j * 32 + lane], dacc0);
    atomicAdd(&den[b * N_ + jw + wqk_j * 32 + 16 + lane], dacc1);
  }

  // ---- numerator partial epilogue: LDS transpose -> coalesced [n][c] bf16 ----
  // q_lds region is free (all QK reads finished before the last barrier).
  // Wave's acc covers c = wpv_c*64 + m*16 + quad*4 + r, j_loc = wpv_j*64... NO:
  // wave's PV tj-range is wpv_j*64 + t*16 + l16 (64 wide) but blocks are 128
  // wide; two waves (wpv_j 0/1) share each c-range. ep tile: [128 j][256 c]
  // doesn't fit; do it in two 64-j halves.
  ushort* rp = (seg ? res1 : res0) + (size_t)(b * N_ + jw) * C_;
  #pragma unroll
  for (int half = 0; half < 2; ++half) {
    __syncthreads();   // previous half's global reads of q_lds done / PV done
    if (wpv_j == half) {
      #pragma unroll
      for (int m = 0; m < 4; ++m) {
        const int c0 = wpv_c * 64 + m * 16 + quad * 4;
        #pragma unroll
        for (int t = 0; t < 4; ++t) {
          const int j_loc = t * 16 + l16;
          *(ushort4*)&q_lds[j_loc * 264 + c0] =
              make_ushort4(f2bf(acc[m][t][0]), f2bf(acc[m][t][1]),
                           f2bf(acc[m][t][2]), f2bf(acc[m][t][3]));
        }
      }
    }
    __syncthreads();   // half's tile assembled
    // cooperative coalesced store: 64 rows x 512 B, 16B/lane
    {
      const int jbase = half * 64;
      #pragma unroll
      for (int k = 0; k < 4; ++k) {
        int c = tid + k * 512;               // 2048 16B-chunks
        int row = c >> 5, col = (c & 31) * 8;
        uint4 d = *(const uint4*)&q_lds[row * 264 + col];
        *(uint4*)&rp[(size_t)(jbase + row) * C_ + col] = d;
      }
    }
  }
}

// ---------------------------------------------------------------------------
// out_mfma: out[b][co][n] = bo[co] + Wo[co][:]·(res0+res1)[b][n][:] / den[b][n]
// (unchanged from R7, passing). grid (16, 4, 4), block 256.
// ---------------------------------------------------------------------------
__global__ __launch_bounds__(256, 2) void out_mfma(
    const ushort* __restrict__ res0, const ushort* __restrict__ res1,
    const float* __restrict__ Wo, const float* __restrict__ bo,
    const float* __restrict__ den, float* __restrict__ out)
{
  const int b    = blockIdx.z;
  const int co0  = blockIdx.y * 64;
  const int nseg = blockIdx.x * 256;

  const int tid  = threadIdx.x;
  const int lane = tid & 63;
  const int wave = tid >> 6;
  const int l16  = lane & 15;
  const int quad = lane >> 4;

  __shared__ __align__(16) ushort w_lds[64 * 264];
  __shared__ __align__(16) ushort r_lds[2][64 * 264];

  for (int g = tid; g < 4096; g += 256) {
    int row = g >> 6, col4 = (g & 63) * 4;
    float4 wv = *(const float4*)(Wo + (size_t)(co0 + row) * 256 + col4);
    *(ushort4*)&w_lds[row * 264 + col4] =
        make_ushort4(f2bf(wv.x), f2bf(wv.y), f2bf(wv.z), f2bf(wv.w));
  }
  __syncthreads();

  s8v kw[4][8];
  #pragma unroll
  for (int lt = 0; lt < 4; ++lt)
    #pragma unroll
    for (int cs = 0; cs < 8; ++cs)
      kw[lt][cs] = *(const s8v*)&w_lds[(lt * 16 + l16) * 264 + quad * 8 + cs * 32];

  float bias_l[4];
  #pragma unroll
  for (int lt = 0; lt < 4; ++lt) bias_l[lt] = bo[co0 + lt * 16 + l16];

  for (int it = 0; it < 4; ++it) {
    const int n0 = nseg + it * 64;
    {
      const ushort* r0 = res0 + (size_t)(b * N_ + n0) * C_;
      const ushort* r1 = res1 + (size_t)(b * N_ + n0) * C_;
      #pragma unroll
      for (int k = 0; k < 8; ++k) {
        int c = tid + k * 256;
        uint4 d0 = *(const uint4*)(r0 + (size_t)c * 8);
        uint4 d1 = *(const uint4*)(r1 + (size_t)c * 8);
        *(uint4*)&r_lds[0][(c >> 5) * 264 + (c & 31) * 8] = d0;
        *(uint4*)&r_lds[1][(c >> 5) * 264 + (c & 31) * 8] = d1;
      }
    }
    __syncthreads();

    f4v s[4];
    #pragma unroll
    for (int lt = 0; lt < 4; ++lt) s[lt] = (f4v){0.f, 0.f, 0.f, 0.f};
    #pragma unroll
    for (int buf = 0; buf < 2; ++buf) {
      const ushort* ra_base = r_lds[buf] + (wave * 16 + l16) * 264 + quad * 8;
      #pragma unroll
      for (int cs = 0; cs < 8; ++cs) {
        s8v ra = *(const s8v*)(ra_base + cs * 32);
        #pragma unroll
        for (int lt = 0; lt < 4; ++lt)
          s[lt] = __builtin_amdgcn_mfma_f32_16x16x32_bf16(ra, kw[lt][cs], s[lt], 0, 0, 0);
      }
    }

    const int nb = n0 + wave * 16 + quad * 4;
    float4 dv = *(const float4*)(den + (size_t)b * N_ + nb);
    const float di0 = 1.0f / dv.x, di1 = 1.0f / dv.y, di2 = 1.0f / dv.z, di3 = 1.0f / dv.w;
    #pragma unroll
    for (int lt = 0; lt < 4; ++lt) {
      const int co = co0 + lt * 16 + l16;
      *(float4*)&out[(size_t)(b * C_ + co) * N_ + nb] =
          make_float4(s[lt][0] * di0 + bias_l[lt], s[lt][1] * di1 + bias_l[lt],
                      s[lt][2] * di2 + bias_l[lt], s[lt][3] * di3 + bias_l[lt]);
    }
    __syncthreads();
  }
}

// ---------------------------------------------------------------------------
extern "C" void kernel_launch(void* const* d_in, const int* in_sizes, int n_in,
                              void* d_out, int out_size, void* d_ws, size_t ws_size,
                              hipStream_t stream)
{
  const float* x  = (const float*)d_in[0];
  const float* Wq = (const float*)d_in[1];
  const float* bq = (const float*)d_in[2];
  const float* Wk = (const float*)d_in[3];
  const float* bk = (const float*)d_in[4];
  const float* Wv = (const float*)d_in[5];
  const float* bv = (const float*)d_in[6];
  const float* Wo = (const float*)d_in[7];
  const float* bo = (const float*)d_in[8];
  float* out = (float*)d_out;

  // workspace layout (~48.1 MB):
  //   q_t   [B][N][L] bf16 : 8 MB   (transposed)
  //   k_t   [B][N][L] bf16 : 8 MB   (transposed)
  //   v_bf  [B][L][N] bf16 : 8 MB   (natural)
  //   res0  [B][N][L] bf16 : 8 MB   (numerator partial, i-segment 0)
  //   res1  [B][N][L] bf16 : 8 MB   (numerator partial, i-segment 1)
  //   den   [B][N]    fp32 : 64 KB  (softmax denominators, atomic target)
  //   x_t   [B][N][C] bf16 : 8 MB   (transposed+cast input)
  char* ws = (char*)d_ws;
  ushort* q_t  = (ushort*)(ws);
  ushort* k_t  = (ushort*)(ws + (size_t)8  * 1024 * 1024);
  ushort* v_bf = (ushort*)(ws + (size_t)16 * 1024 * 1024);
  ushort* res0 = (ushort*)(ws + (size_t)24 * 1024 * 1024);
  ushort* res1 = (ushort*)(ws + (size_t)32 * 1024 * 1024);
  float*  den  = (float*) (ws + (size_t)40 * 1024 * 1024);
  ushort* x_t  = (ushort*)(ws + (size_t)40 * 1024 * 1024 + 65536);

  // only den needs zeroing (res partials are fully overwritten)
  (void)hipMemsetAsync(den, 0, (size_t)B_ * N_ * sizeof(float), stream);

  xpose_cast<<<dim3(64, 4, 4), dim3(256), 0, stream>>>(x, x_t);
  qkv_mfma <<<dim3(8, 4, 12),  dim3(256), 0, stream>>>(x_t, Wq, bq, Wk, bk, Wv, bv, q_t, k_t, v_bf);
  flash7   <<<dim3(32, 2, 4),  dim3(512), 0, stream>>>(q_t, k_t, v_bf, res0, res1, den);
  out_mfma <<<dim3(16, 4, 4),  dim3(256), 0, stream>>>(res0, res1, Wo, bo, den, out);
}